// Round 14
// baseline (411.013 us; speedup 1.0000x reference)
//
#include <hip/hip_runtime.h>
#include <hip/hip_bf16.h>
#include <math.h>

#define BB 2
#define NN 2048
#define DD 512
#define HH 8
#define LL 2
#define TT (BB*NN)   // 4096 tokens

typedef short short8 __attribute__((ext_vector_type(8)));
typedef float floatx4 __attribute__((ext_vector_type(4)));

__device__ __forceinline__ unsigned short f2b(float v) {
    union { float f; unsigned u; } x; x.f = v;
    unsigned r = x.u + 0x7fff + ((x.u >> 16) & 1);   // RNE
    return (unsigned short)(r >> 16);
}

// global -> LDS direct DMA, 16B/lane. LDS dest is wave-uniform base + lane*16 (HW rule);
// global src is per-lane. Each lane DMAs exactly its own MFMA fragment.
__device__ __forceinline__ void gld16(const unsigned short* g, unsigned short* lds) {
    __builtin_amdgcn_global_load_lds(
        (const __attribute__((address_space(1))) unsigned int*)g,
        (__attribute__((address_space(3))) unsigned int*)lds,
        16, 0, 0);
}

// ---------------- dst = src + bias (row-broadcast); src may alias dst ----------------
__global__ __launch_bounds__(256) void k_bias_add(const float* __restrict__ src,
                                                  const float* __restrict__ bias,
                                                  float* __restrict__ dst) {
    int i = blockIdx.x * 256 + threadIdx.x;
    dst[i] = src[i] + bias[i & (DD - 1)];
}

// ---------------- layernorm (opt. fused embed): x = LN(src)*g + b (bf16) ----------------
// EMB: src = emb + pos (also written to hout for the residual stream); else src = hin.
template <int EMB>
__global__ __launch_bounds__(256) void k_ln(const float* __restrict__ hin,
                                            unsigned short* __restrict__ xout,
                                            const float* __restrict__ g,
                                            const float* __restrict__ b,
                                            const float* __restrict__ emb,
                                            const float* __restrict__ pos,
                                            float* __restrict__ hout) {
    __shared__ float red[4];
    __shared__ float bc1, bc2;
    int t = blockIdx.x;
    int tid = threadIdx.x;
    int lane = tid & 63, wv = tid >> 6;
    float v0, v1;
    if (EMB) {
        const float* erow = emb + (size_t)t * DD;
        const float* prow = pos + (size_t)(t & (NN - 1)) * DD;
        v0 = erow[tid] + prow[tid];
        v1 = erow[tid + 256] + prow[tid + 256];
        hout[(size_t)t * DD + tid] = v0;
        hout[(size_t)t * DD + tid + 256] = v1;
    } else {
        const float* row = hin + (size_t)t * DD;
        v0 = row[tid];
        v1 = row[tid + 256];
    }

    float s = v0 + v1;
#pragma unroll
    for (int o = 32; o; o >>= 1) s += __shfl_down(s, o, 64);
    if (lane == 0) red[wv] = s;
    __syncthreads();
    if (tid == 0) bc1 = (red[0] + red[1] + red[2] + red[3]) * (1.0f / DD);
    __syncthreads();
    float mu = bc1;
    float d0 = v0 - mu, d1 = v1 - mu;
    s = d0 * d0 + d1 * d1;
#pragma unroll
    for (int o = 32; o; o >>= 1) s += __shfl_down(s, o, 64);
    if (lane == 0) red[wv] = s;
    __syncthreads();
    if (tid == 0) bc2 = (red[0] + red[1] + red[2] + red[3]) * (1.0f / DD);
    __syncthreads();
    float rstd = rsqrtf(bc2 + 1e-5f);
    xout[(size_t)t * DD + tid]       = f2b(d0 * rstd * g[tid] + b[tid]);
    xout[(size_t)t * DD + tid + 256] = f2b(d1 * rstd * g[tid + 256] + b[tid + 256]);
}

// gelu_new via exact identity: 0.5v(1+tanh(u)) = v * e2u/(e2u+1), e2u = exp2(2u*log2e).
__device__ __forceinline__ float gelu_new(float v) {
    const float c = 0.7978845608028654f;   // sqrt(2/pi)
    float u = c * (v + 0.044715f * v * v * v);
    u = fminf(fmaxf(u, -30.0f), 30.0f);    // avoid exp2 overflow; exact within bf16 anyway
    float e = __builtin_amdgcn_exp2f(2.885390081777927f * u);   // exp(2u)
    return v * e * __builtin_amdgcn_rcpf(e + 1.0f);
}

// ---------------- all-weight transpose+convert, both layers, one dispatch ----------------
#define PL 3145728   // per-layer bf16 WT region (elements)
__global__ __launch_bounds__(256) void k_wt_all(const float* __restrict__ c_attn_w,
                                                const float* __restrict__ out_w,
                                                const float* __restrict__ c_fc_w,
                                                const float* __restrict__ c_proj_w,
                                                unsigned short* __restrict__ wbuf) {
    __shared__ unsigned short t[64][72];
    int bx = blockIdx.x;
    int l = bx / 768;
    int r = bx - l * 768;
    const float* W; unsigned short* WT; int K, N;
    if (r < 192)      { W = c_attn_w + (size_t)l * 512 * 1536; WT = wbuf + (size_t)l * PL;           K = 512;  N = 1536; }
    else if (r < 256) { r -= 192; W = out_w  + (size_t)l * 512 * 512;  WT = wbuf + (size_t)l * PL + 786432;  K = 512;  N = 512; }
    else if (r < 512) { r -= 256; W = c_fc_w + (size_t)l * 512 * 2048; WT = wbuf + (size_t)l * PL + 1048576; K = 512;  N = 2048; }
    else              { r -= 512; W = c_proj_w + (size_t)l * 2048 * 512; WT = wbuf + (size_t)l * PL + 2097152; K = 2048; N = 512; }
    int tiles_n = N >> 6;
    int n0 = (r % tiles_n) * 64, k0 = (r / tiles_n) * 64;

    int tid = threadIdx.x;
    int rr = tid >> 2;
    int c0 = (tid & 3) * 16;
    const float* src = W + (size_t)(k0 + rr) * N + n0 + c0;
#pragma unroll
    for (int u = 0; u < 4; u++) {
        float4 v = *(const float4*)&src[u * 4];
        t[c0 + u * 4 + 0][rr] = f2b(v.x);
        t[c0 + u * 4 + 1][rr] = f2b(v.y);
        t[c0 + u * 4 + 2][rr] = f2b(v.z);
        t[c0 + u * 4 + 3][rr] = f2b(v.w);
    }
    __syncthreads();
    unsigned short* dst = WT + (size_t)(n0 + rr) * K + k0 + c0;
#pragma unroll
    for (int u = 0; u < 4; u++)
        *(uint2*)&dst[u * 4] = *(const uint2*)&t[rr][c0 + u * 4];
}

// ---------------- MFMA GEMM: 128x128 tile, 8 waves, BK=64, XCD-swizzled grid -------------
// (round-11/12 measured-best structure; unchanged this round)
template <int ACT, int BF16OUT, int ATOMIC>
__global__ __launch_bounds__(512) void k_mgemm(const unsigned short* __restrict__ Ab,
                                               const unsigned short* __restrict__ Bt,
                                               const float* __restrict__ bias,
                                               float* __restrict__ Cp,
                                               unsigned short* __restrict__ Cb,
                                               int Kfull, int Kchunk, int N) {
    __shared__ unsigned short Als[2][16 * 512];  // 16 KB per buffer
    __shared__ unsigned short Bls[2][16 * 512];

    int tid = threadIdx.x;
    int l = tid & 63, w = tid >> 6;          // 8 waves
    int wm = w >> 2, wn = w & 3;             // 2 (M) x 4 (N)

    // XCD-aware bijective swizzle of the block index (T1)
    int nx = gridDim.x, ny = gridDim.y;
    int flat = (blockIdx.z * ny + blockIdx.y) * nx + blockIdx.x;
    int cpx = (nx * ny * gridDim.z) >> 3;    // blocks per XCD chunk
    int swz = (flat & 7) * cpx + (flat >> 3);
    int nxy = nx * ny;
    int bz = swz / nxy;
    int bxy = swz - bz * nxy;
    int by = bxy / nx;
    int bx = bxy - by * nx;

    int m0 = by * 128, n0 = bx * 128;
    int kb = bz * Kchunk;
    int lr = l & 15;
    int lk = (l >> 4) * 8;

    const unsigned short* Ap = Ab + (size_t)(m0 + w * 16 + lr) * Kfull + kb + lk;
    const unsigned short* Bp = Bt + (size_t)(n0 + w * 16 + lr) * Kfull + kb + lk;
    unsigned short* lsA = &Als[0][0];
    unsigned short* lsB = &Bls[0][0];
    int wbase = w << 9;                      // w*512 shorts
    const int KH = 8 * 512;                  // k-half stride: 4096 shorts
    const int BUF = 16 * 512;                // buffer stride: 8192 shorts

    floatx4 acc[4][2];
#pragma unroll
    for (int i = 0; i < 4; i++)
#pragma unroll
        for (int j = 0; j < 2; j++) acc[i][j] = (floatx4){0.f, 0.f, 0.f, 0.f};

    int nit = Kchunk >> 6;                   // K-step = 64

    // prologue: DMA tile 0 (both k-halves) -> buf0; barrier drains vmcnt
    gld16(Ap,      lsA + wbase);
    gld16(Ap + 32, lsA + KH + wbase);
    gld16(Bp,      lsB + wbase);
    gld16(Bp + 32, lsB + KH + wbase);
    __syncthreads();

    for (int it = 0; it < nit; it++) {
        int c = it & 1;
        if (it + 1 < nit) {          // buf c^1 free (its readers passed the previous barrier)
            int ko = (it + 1) << 6;
            int db = (c ^ 1) * BUF;
            gld16(Ap + ko,      lsA + db + wbase);
            gld16(Ap + ko + 32, lsA + db + KH + wbase);
            gld16(Bp + ko,      lsB + db + wbase);
            gld16(Bp + ko + 32, lsB + db + KH + wbase);
        }
        int cb = c * BUF;
#pragma unroll
        for (int kk = 0; kk < 2; kk++) {
            short8 a[4], b[2];
            int ko = cb + kk * KH;
#pragma unroll
            for (int i = 0; i < 4; i++)
                a[i] = *(const short8*)&lsA[ko + (wm * 4 + i) * 512 + l * 8];
#pragma unroll
            for (int j = 0; j < 2; j++)
                b[j] = *(const short8*)&lsB[ko + (wn * 2 + j) * 512 + l * 8];
#pragma unroll
            for (int i = 0; i < 4; i++)
#pragma unroll
                for (int j = 0; j < 2; j++)
                    acc[i][j] = __builtin_amdgcn_mfma_f32_16x16x32_bf16(a[i], b[j], acc[i][j], 0, 0, 0);
        }
        __syncthreads();             // readers of buf c done + prefetch (buf c^1) drained
    }

    // epilogue: C/D layout col=lane&15, row=(lane>>4)*4+reg
    int col_in = l & 15, rquad = (l >> 4) * 4;
    bool addb = (!ATOMIC) || (bias != nullptr && bz == 0);
#pragma unroll
    for (int i = 0; i < 4; i++) {
        int gm_base = m0 + wm * 64 + i * 16 + rquad;
#pragma unroll
        for (int j = 0; j < 2; j++) {
            int gn = n0 + wn * 32 + j * 16 + col_in;
            float bv = addb ? bias[gn] : 0.0f;
#pragma unroll
            for (int r = 0; r < 4; r++) {
                size_t off = (size_t)(gm_base + r) * N + gn;
                if (ATOMIC) {
                    atomicAdd(&Cp[off], acc[i][j][r] + bv);
                } else {
                    float v = acc[i][j][r] + bv;
                    if (ACT) v = gelu_new(v);
                    if (BF16OUT) Cb[off] = f2b(v);
                    else Cp[off] = v;
                }
            }
        }
    }
}

// ---------------- MFMA flash attention: K/V dbuf, XCD swizzle, STRIDE-68 LDS -------------
// Pad 72 -> 68 shorts (136 B = 34 dwords === 2 mod 32 banks). At stride 72 (=== 4 mod 32)
// the V-transpose staging writes hit only 8 banks for 64 lanes (16-way conflict, 4x over
// floor) -- the measured 5.77M SQ_LDS_BANK_CONFLICT (~21% of CU cycles). At 68 all five
// access patterns (K/V/P b128 reads, K uint4 / V,P uint2 writes) sit at the bank floor.
// Everything else identical to the round-13 measured-best body.
__global__ __launch_bounds__(256) void k_attn_mfma(const unsigned short* __restrict__ qkv,
                                                   unsigned short* __restrict__ xatt) {
    __shared__ unsigned short Ks[2][64 * 68];    // K tile [key][d], double-buffered
    __shared__ unsigned short Vt[2][64 * 68];    // V^T tile [d][key], double-buffered
    __shared__ unsigned short Pls[64 * 68];      // P tile [m][key] (wave-private rows)

    // grid (32, 8, 2), nwg=512, cpx=64 -- bijective XCD swizzle
    int flat = (blockIdx.z * HH + blockIdx.y) * (NN / 64) + blockIdx.x;
    int swz = (flat & 7) * 64 + (flat >> 3);
    int qt = swz & 31;
    int hb = swz >> 5;
    int hd = hb & 7, b = hb >> 3;

    int tid = threadIdx.x;
    int l = tid & 63, w = tid >> 6;
    int lr = l & 15, quad = l >> 4;

    const size_t base = (size_t)b * NN * 1536;

    // Q frags (B-operand): lane col m=lr, k=d=quad*8+j (+32*ss)
    short8 qf[2];
    {
        const unsigned short* qrow = qkv + base + (size_t)(qt * 64 + w * 16 + lr) * 1536 + hd * 64;
        qf[0] = *(const short8*)&qrow[quad * 8];
        qf[1] = *(const short8*)&qrow[quad * 8 + 32];
    }

    floatx4 O[4];   // O[m=quad*4+reg][d=jd*16+lr]
#pragma unroll
    for (int jd = 0; jd < 4; jd++) O[jd] = (floatx4){0.f, 0.f, 0.f, 0.f};
    float lsum = 0.0f;   // per-lane partial row-sum for query m = w*16+lr

    // staging maps; running pointers bumped by constant stride (cheap VALU)
    int sr = tid >> 2, sc = (tid & 3) * 16;          // K: row sr (key), 16-d chunk sc
    int vk = (tid & 15) * 4, vd = (tid >> 4) * 4;    // V: 4 keys x 4 d per thread
    const int STEP = 64 * 1536;                      // one 64-key tile
    const unsigned short* Kp = qkv + base + 512 + hd * 64 + (size_t)sr * 1536 + sc;
    const unsigned short* Vp = qkv + base + 1024 + hd * 64 + (size_t)vk * 1536 + vd;

    uint4 rk0, rk1;
    union { uint2 u; unsigned short s[4]; } rv[4];

    // prologue: load tile 0, write to buf 0, load tile 1, barrier
    rk0 = *(const uint4*)Kp;
    rk1 = *(const uint4*)(Kp + 8);
#pragma unroll
    for (int i = 0; i < 4; i++)
        rv[i].u = *(const uint2*)(Vp + (size_t)i * 1536);
    *(uint4*)&Ks[0][sr * 68 + sc]     = rk0;
    *(uint4*)&Ks[0][sr * 68 + sc + 8] = rk1;
#pragma unroll
    for (int j = 0; j < 4; j++) {
        union { uint2 u; unsigned short s[4]; } pk;
        pk.s[0] = rv[0].s[j]; pk.s[1] = rv[1].s[j];
        pk.s[2] = rv[2].s[j]; pk.s[3] = rv[3].s[j];
        *(uint2*)&Vt[0][(vd + j) * 68 + vk] = pk.u;
    }
    Kp += STEP; Vp += STEP;
    rk0 = *(const uint4*)Kp;
    rk1 = *(const uint4*)(Kp + 8);
#pragma unroll
    for (int i = 0; i < 4; i++)
        rv[i].u = *(const uint2*)(Vp + (size_t)i * 1536);
    __syncthreads();

    // exp(s/8 - 8) = exp2(s * (0.125*log2e) - 8*log2e)
    const float EC1 = 0.18033688011112042f;
    const float EC0 = -11.541560327111707f;

    for (int kt = 0; kt < 32; kt++) {
        int c = kt & 1;

        // S^T = K Q^T: s[jn] rows key=jn*16+quad*4+reg, col m=lr
        floatx4 s[4];
#pragma unroll
        for (int jn = 0; jn < 4; jn++) s[jn] = (floatx4){0.f, 0.f, 0.f, 0.f};
#pragma unroll
        for (int ss = 0; ss < 2; ss++)
#pragma unroll
            for (int jn = 0; jn < 4; jn++) {
                short8 ak = *(const short8*)&Ks[c][(jn * 16 + lr) * 68 + ss * 32 + quad * 8];
                s[jn] = __builtin_amdgcn_mfma_f32_16x16x32_bf16(ak, qf[ss], s[jn], 0, 0, 0);
            }

        // p = exp2(s*EC1 + EC0); diag mask (uniform branch, 1/32 iters); lsum; pk pack
        int mq = w * 16 + lr;   // query index within 64-row q tile
        bool diag = (kt == qt);
#pragma unroll
        for (int jn = 0; jn < 4; jn++) {
            float p0 = __builtin_amdgcn_exp2f(fmaf(s[jn][0], EC1, EC0));
            float p1 = __builtin_amdgcn_exp2f(fmaf(s[jn][1], EC1, EC0));
            float p2 = __builtin_amdgcn_exp2f(fmaf(s[jn][2], EC1, EC0));
            float p3 = __builtin_amdgcn_exp2f(fmaf(s[jn][3], EC1, EC0));
            if (diag) {   // wave-uniform: taken in exactly one kt iteration
                int kbase = jn * 16 + quad * 4;
                if (mq == kbase + 0) p0 = 0.0f;
                if (mq == kbase + 1) p1 = 0.0f;
                if (mq == kbase + 2) p2 = 0.0f;
                if (mq == kbase + 3) p3 = 0.0f;
            }
            lsum += (p0 + p1) + (p2 + p3);
            unsigned w01, w23;
            asm("v_cvt_pk_bf16_f32 %0, %1, %2" : "=v"(w01) : "v"(p0), "v"(p1));
            asm("v_cvt_pk_bf16_f32 %0, %1, %2" : "=v"(w23) : "v"(p2), "v"(p3));
            uint2 pku; pku.x = w01; pku.y = w23;
            *(uint2*)&Pls[mq * 68 + jn * 16 + quad * 4] = pku;
        }

        // O += P V   (P rows written/read by the same wave; no barrier needed)
#pragma unroll
        for (int ss = 0; ss < 2; ss++) {
            short8 ap = *(const short8*)&Pls[(w * 16 + lr) * 68 + ss * 32 + quad * 8];
#pragma unroll
            for (int jd = 0; jd < 4; jd++) {
                short8 bv = *(const short8*)&Vt[c][(jd * 16 + lr) * 68 + ss * 32 + quad * 8];
                O[jd] = __builtin_amdgcn_mfma_f32_16x16x32_bf16(ap, bv, O[jd], 0, 0, 0);
            }
        }

        // stage tile kt+1 (in regs) -> other buffer; then load tile kt+2
        if (kt < 31) {
            *(uint4*)&Ks[c ^ 1][sr * 68 + sc]     = rk0;
            *(uint4*)&Ks[c ^ 1][sr * 68 + sc + 8] = rk1;
#pragma unroll
            for (int j = 0; j < 4; j++) {
                union { uint2 u; unsigned short s[4]; } pk;
                pk.s[0] = rv[0].s[j]; pk.s[1] = rv[1].s[j];
                pk.s[2] = rv[2].s[j]; pk.s[3] = rv[3].s[j];
                *(uint2*)&Vt[c ^ 1][(vd + j) * 68 + vk] = pk.u;
            }
            if (kt < 30) {
                Kp += STEP; Vp += STEP;
                rk0 = *(const uint4*)Kp;
                rk1 = *(const uint4*)(Kp + 8);
#pragma unroll
                for (int i = 0; i < 4; i++)
                    rv[i].u = *(const uint2*)(Vp + (size_t)i * 1536);
            }
        }
        __syncthreads();   // buf c readers done + buf c^1 fully written
    }

    // reduce lsum across quads (lanes lr, lr+16, lr+32, lr+48 hold same query)
    lsum += __shfl_xor(lsum, 16);
    lsum += __shfl_xor(lsum, 32);
#pragma unroll
    for (int r = 0; r < 4; r++) {
        float inv = 1.0f / __shfl(lsum, quad * 4 + r, 16);
        size_t tok = (size_t)b * NN + qt * 64 + w * 16 + quad * 4 + r;
#pragma unroll
        for (int jd = 0; jd < 4; jd++)
            xatt[tok * DD + hd * 64 + jd * 16 + lr] = f2b(O[jd][r] * inv);
    }
}

extern "C" void kernel_launch(void* const* d_in, const int* in_sizes, int n_in,
                              void* d_out, int out_size, void* d_ws, size_t ws_size,
                              hipStream_t stream) {
    const float* emb      = (const float*)d_in[0];
    const float* pos      = (const float*)d_in[1];
    const float* c_attn_w = (const float*)d_in[2];
    const float* c_attn_b = (const float*)d_in[3];
    const float* out_w    = (const float*)d_in[4];
    const float* out_b    = (const float*)d_in[5];
    const float* ln1_g    = (const float*)d_in[6];
    const float* ln1_b    = (const float*)d_in[7];
    const float* c_fc_w   = (const float*)d_in[8];
    const float* c_fc_b   = (const float*)d_in[9];
    const float* c_proj_w = (const float*)d_in[10];
    const float* c_proj_b = (const float*)d_in[11];
    const float* ln2_g    = (const float*)d_in[12];
    const float* ln2_b    = (const float*)d_in[13];

    // workspace: 8 + 16.8 + 4 + 4 + 12.6 = ~45.4 MB
    char* p = (char*)d_ws;
    float* h = (float*)p;                       p += (size_t)TT * DD * 4;      // fp32 residual
    unsigned short* act = (unsigned short*)p;   p += (size_t)TT * 2048 * 2;    // qkvb/ffa union
    unsigned short* x = (unsigned short*)p;     p += (size_t)TT * DD * 2;      // LN out
    unsigned short* xatt = (unsigned short*)p;  p += (size_t)TT * DD * 2;      // attn out
    unsigned short* wbuf = (unsigned short*)p;                                 // bf16 W^T (both layers)

    unsigned short* qkvb = act;
    unsigned short* ffa  = act;
    float* out = (float*)d_out;

    k_wt_all<<<1536, 256, 0, stream>>>(c_attn_w, out_w, c_fc_w, c_proj_w, wbuf);

    for (int l = 0; l < LL; l++) {
        unsigned short* wqkv_t  = wbuf + (size_t)l * PL;
        unsigned short* wout_t  = wqkv_t + 786432;
        unsigned short* wfc_t   = wqkv_t + 1048576;
        unsigned short* wproj_t = wqkv_t + 2097152;

        // x = LN1(h)  (layer 0: fused embed, also writes h)
        if (l == 0)
            k_ln<1><<<TT, 256, 0, stream>>>(nullptr, x, ln1_g, ln1_b, emb, pos, h);
        else
            k_ln<0><<<TT, 256, 0, stream>>>(h, x, ln1_g + l * DD, ln1_b + l * DD,
                                            nullptr, nullptr, nullptr);
        // qkvb = x @ Wqkv + b  (bf16)
        k_mgemm<0, 1, 0><<<dim3(1536 / 128, TT / 128), 512, 0, stream>>>(
            x, wqkv_t, c_attn_b + l * 1536, nullptr, qkvb, 512, 512, 1536);
        // xatt = attention(qkvb)  (bf16)
        k_attn_mfma<<<dim3(NN / 64, HH, BB), 256, 0, stream>>>(qkvb, xatt);
        // h += xatt @ Wout + out_b  (split-K=2 fp32 atomics; bias folded into z==0)
        k_mgemm<0, 0, 1><<<dim3(512 / 128, TT / 128, 2), 512, 0, stream>>>(
            xatt, wout_t, out_b + l * DD, h, nullptr, 512, 256, 512);
        // x = LN2(h)
        k_ln<0><<<TT, 256, 0, stream>>>(h, x, ln2_g + l * DD, ln2_b + l * DD,
                                        nullptr, nullptr, nullptr);
        // ffa = gelu(x @ Wfc + b)  (bf16; qkvb dead)
        k_mgemm<1, 1, 0><<<dim3(2048 / 128, TT / 128), 512, 0, stream>>>(
            x, wfc_t, c_fc_b + l * 2048, nullptr, ffa, 512, 512, 2048);
        // h/out += ffa @ Wproj + proj_b  (split-K=4 fp32 atomics)
        if (l == LL - 1) {
            k_bias_add<<<TT * DD / 256, 256, 0, stream>>>(h, c_proj_b + l * DD, out);
            k_mgemm<0, 0, 1><<<dim3(512 / 128, TT / 128, 4), 512, 0, stream>>>(
                ffa, wproj_t, nullptr, out, nullptr, 2048, 512, 512);
        } else {
            k_mgemm<0, 0, 1><<<dim3(512 / 128, TT / 128, 4), 512, 0, stream>>>(
                ffa, wproj_t, c_proj_b + l * DD, h, nullptr, 2048, 512, 512);
        }
    }
}

// Round 16
// 409.057 us; speedup vs baseline: 1.0048x; 1.0048x over previous
//
#include <hip/hip_runtime.h>
#include <hip/hip_bf16.h>
#include <math.h>

#define BB 2
#define NN 2048
#define DD 512
#define HH 8
#define LL 2
#define TT (BB*NN)   // 4096 tokens

typedef short short8 __attribute__((ext_vector_type(8)));
typedef float floatx4 __attribute__((ext_vector_type(4)));

__device__ __forceinline__ unsigned short f2b(float v) {
    union { float f; unsigned u; } x; x.f = v;
    unsigned r = x.u + 0x7fff + ((x.u >> 16) & 1);   // RNE
    return (unsigned short)(r >> 16);
}

// global -> LDS direct DMA, 16B/lane. LDS dest is wave-uniform base + lane*16 (HW rule);
// global src is per-lane. Each lane DMAs exactly its own MFMA fragment.
__device__ __forceinline__ void gld16(const unsigned short* g, unsigned short* lds) {
    __builtin_amdgcn_global_load_lds(
        (const __attribute__((address_space(1))) unsigned int*)g,
        (__attribute__((address_space(3))) unsigned int*)lds,
        16, 0, 0);
}

// ---------------- dst = src + bias (row-broadcast); src may alias dst ----------------
__global__ __launch_bounds__(256) void k_bias_add(const float* __restrict__ src,
                                                  const float* __restrict__ bias,
                                                  float* __restrict__ dst) {
    int i = blockIdx.x * 256 + threadIdx.x;
    dst[i] = src[i] + bias[i & (DD - 1)];
}

// ---------------- layernorm (opt. fused embed): x = LN(src)*g + b (bf16) ----------------
// EMB: src = emb + pos (also written to hout for the residual stream); else src = hin.
template <int EMB>
__global__ __launch_bounds__(256) void k_ln(const float* __restrict__ hin,
                                            unsigned short* __restrict__ xout,
                                            const float* __restrict__ g,
                                            const float* __restrict__ b,
                                            const float* __restrict__ emb,
                                            const float* __restrict__ pos,
                                            float* __restrict__ hout) {
    __shared__ float red[4];
    __shared__ float bc1, bc2;
    int t = blockIdx.x;
    int tid = threadIdx.x;
    int lane = tid & 63, wv = tid >> 6;
    float v0, v1;
    if (EMB) {
        const float* erow = emb + (size_t)t * DD;
        const float* prow = pos + (size_t)(t & (NN - 1)) * DD;
        v0 = erow[tid] + prow[tid];
        v1 = erow[tid + 256] + prow[tid + 256];
        hout[(size_t)t * DD + tid] = v0;
        hout[(size_t)t * DD + tid + 256] = v1;
    } else {
        const float* row = hin + (size_t)t * DD;
        v0 = row[tid];
        v1 = row[tid + 256];
    }

    float s = v0 + v1;
#pragma unroll
    for (int o = 32; o; o >>= 1) s += __shfl_down(s, o, 64);
    if (lane == 0) red[wv] = s;
    __syncthreads();
    if (tid == 0) bc1 = (red[0] + red[1] + red[2] + red[3]) * (1.0f / DD);
    __syncthreads();
    float mu = bc1;
    float d0 = v0 - mu, d1 = v1 - mu;
    s = d0 * d0 + d1 * d1;
#pragma unroll
    for (int o = 32; o; o >>= 1) s += __shfl_down(s, o, 64);
    if (lane == 0) red[wv] = s;
    __syncthreads();
    if (tid == 0) bc2 = (red[0] + red[1] + red[2] + red[3]) * (1.0f / DD);
    __syncthreads();
    float rstd = rsqrtf(bc2 + 1e-5f);
    xout[(size_t)t * DD + tid]       = f2b(d0 * rstd * g[tid] + b[tid]);
    xout[(size_t)t * DD + tid + 256] = f2b(d1 * rstd * g[tid + 256] + b[tid + 256]);
}

// gelu_new via exact identity: 0.5v(1+tanh(u)) = v * e2u/(e2u+1), e2u = exp2(2u*log2e).
__device__ __forceinline__ float gelu_new(float v) {
    const float c = 0.7978845608028654f;   // sqrt(2/pi)
    float u = c * (v + 0.044715f * v * v * v);
    u = fminf(fmaxf(u, -30.0f), 30.0f);    // avoid exp2 overflow; exact within bf16 anyway
    float e = __builtin_amdgcn_exp2f(2.885390081777927f * u);   // exp(2u)
    return v * e * __builtin_amdgcn_rcpf(e + 1.0f);
}

// ---------------- all-weight transpose+convert, both layers, one dispatch ----------------
#define PL 3145728   // per-layer bf16 WT region (elements)
__global__ __launch_bounds__(256) void k_wt_all(const float* __restrict__ c_attn_w,
                                                const float* __restrict__ out_w,
                                                const float* __restrict__ c_fc_w,
                                                const float* __restrict__ c_proj_w,
                                                unsigned short* __restrict__ wbuf) {
    __shared__ unsigned short t[64][72];
    int bx = blockIdx.x;
    int l = bx / 768;
    int r = bx - l * 768;
    const float* W; unsigned short* WT; int K, N;
    if (r < 192)      { W = c_attn_w + (size_t)l * 512 * 1536; WT = wbuf + (size_t)l * PL;           K = 512;  N = 1536; }
    else if (r < 256) { r -= 192; W = out_w  + (size_t)l * 512 * 512;  WT = wbuf + (size_t)l * PL + 786432;  K = 512;  N = 512; }
    else if (r < 512) { r -= 256; W = c_fc_w + (size_t)l * 512 * 2048; WT = wbuf + (size_t)l * PL + 1048576; K = 512;  N = 2048; }
    else              { r -= 512; W = c_proj_w + (size_t)l * 2048 * 512; WT = wbuf + (size_t)l * PL + 2097152; K = 2048; N = 512; }
    int tiles_n = N >> 6;
    int n0 = (r % tiles_n) * 64, k0 = (r / tiles_n) * 64;

    int tid = threadIdx.x;
    int rr = tid >> 2;
    int c0 = (tid & 3) * 16;
    const float* src = W + (size_t)(k0 + rr) * N + n0 + c0;
#pragma unroll
    for (int u = 0; u < 4; u++) {
        float4 v = *(const float4*)&src[u * 4];
        t[c0 + u * 4 + 0][rr] = f2b(v.x);
        t[c0 + u * 4 + 1][rr] = f2b(v.y);
        t[c0 + u * 4 + 2][rr] = f2b(v.z);
        t[c0 + u * 4 + 3][rr] = f2b(v.w);
    }
    __syncthreads();
    unsigned short* dst = WT + (size_t)(n0 + rr) * K + k0 + c0;
#pragma unroll
    for (int u = 0; u < 4; u++)
        *(uint2*)&dst[u * 4] = *(const uint2*)&t[rr][c0 + u * 4];
}

// ---------------- MFMA GEMM: 128x128 tile, 8 waves, BK=64, XCD-swizzled grid -------------
// (round-11/13 measured-best structure; unchanged)
template <int ACT, int BF16OUT, int ATOMIC>
__global__ __launch_bounds__(512) void k_mgemm(const unsigned short* __restrict__ Ab,
                                               const unsigned short* __restrict__ Bt,
                                               const float* __restrict__ bias,
                                               float* __restrict__ Cp,
                                               unsigned short* __restrict__ Cb,
                                               int Kfull, int Kchunk, int N) {
    __shared__ unsigned short Als[2][16 * 512];  // 16 KB per buffer
    __shared__ unsigned short Bls[2][16 * 512];

    int tid = threadIdx.x;
    int l = tid & 63, w = tid >> 6;          // 8 waves
    int wm = w >> 2, wn = w & 3;             // 2 (M) x 4 (N)

    // XCD-aware bijective swizzle of the block index (T1)
    int nx = gridDim.x, ny = gridDim.y;
    int flat = (blockIdx.z * ny + blockIdx.y) * nx + blockIdx.x;
    int cpx = (nx * ny * gridDim.z) >> 3;    // blocks per XCD chunk
    int swz = (flat & 7) * cpx + (flat >> 3);
    int nxy = nx * ny;
    int bz = swz / nxy;
    int bxy = swz - bz * nxy;
    int by = bxy / nx;
    int bx = bxy - by * nx;

    int m0 = by * 128, n0 = bx * 128;
    int kb = bz * Kchunk;
    int lr = l & 15;
    int lk = (l >> 4) * 8;

    const unsigned short* Ap = Ab + (size_t)(m0 + w * 16 + lr) * Kfull + kb + lk;
    const unsigned short* Bp = Bt + (size_t)(n0 + w * 16 + lr) * Kfull + kb + lk;
    unsigned short* lsA = &Als[0][0];
    unsigned short* lsB = &Bls[0][0];
    int wbase = w << 9;                      // w*512 shorts
    const int KH = 8 * 512;                  // k-half stride: 4096 shorts
    const int BUF = 16 * 512;                // buffer stride: 8192 shorts

    floatx4 acc[4][2];
#pragma unroll
    for (int i = 0; i < 4; i++)
#pragma unroll
        for (int j = 0; j < 2; j++) acc[i][j] = (floatx4){0.f, 0.f, 0.f, 0.f};

    int nit = Kchunk >> 6;                   // K-step = 64

    // prologue: DMA tile 0 (both k-halves) -> buf0; barrier drains vmcnt
    gld16(Ap,      lsA + wbase);
    gld16(Ap + 32, lsA + KH + wbase);
    gld16(Bp,      lsB + wbase);
    gld16(Bp + 32, lsB + KH + wbase);
    __syncthreads();

    for (int it = 0; it < nit; it++) {
        int c = it & 1;
        if (it + 1 < nit) {          // buf c^1 free (its readers passed the previous barrier)
            int ko = (it + 1) << 6;
            int db = (c ^ 1) * BUF;
            gld16(Ap + ko,      lsA + db + wbase);
            gld16(Ap + ko + 32, lsA + db + KH + wbase);
            gld16(Bp + ko,      lsB + db + wbase);
            gld16(Bp + ko + 32, lsB + db + KH + wbase);
        }
        int cb = c * BUF;
#pragma unroll
        for (int kk = 0; kk < 2; kk++) {
            short8 a[4], b[2];
            int ko = cb + kk * KH;
#pragma unroll
            for (int i = 0; i < 4; i++)
                a[i] = *(const short8*)&lsA[ko + (wm * 4 + i) * 512 + l * 8];
#pragma unroll
            for (int j = 0; j < 2; j++)
                b[j] = *(const short8*)&lsB[ko + (wn * 2 + j) * 512 + l * 8];
#pragma unroll
            for (int i = 0; i < 4; i++)
#pragma unroll
                for (int j = 0; j < 2; j++)
                    acc[i][j] = __builtin_amdgcn_mfma_f32_16x16x32_bf16(a[i], b[j], acc[i][j], 0, 0, 0);
        }
        __syncthreads();             // readers of buf c done + prefetch (buf c^1) drained
    }

    // epilogue: C/D layout col=lane&15, row=(lane>>4)*4+reg
    int col_in = l & 15, rquad = (l >> 4) * 4;
    bool addb = (!ATOMIC) || (bias != nullptr && bz == 0);
#pragma unroll
    for (int i = 0; i < 4; i++) {
        int gm_base = m0 + wm * 64 + i * 16 + rquad;
#pragma unroll
        for (int j = 0; j < 2; j++) {
            int gn = n0 + wn * 32 + j * 16 + col_in;
            float bv = addb ? bias[gn] : 0.0f;
#pragma unroll
            for (int r = 0; r < 4; r++) {
                size_t off = (size_t)(gm_base + r) * N + gn;
                if (ATOMIC) {
                    atomicAdd(&Cp[off], acc[i][j][r] + bv);
                } else {
                    float v = acc[i][j][r] + bv;
                    if (ACT) v = gelu_new(v);
                    if (BF16OUT) Cb[off] = f2b(v);
                    else Cp[off] = v;
                }
            }
        }
    }
}

// ---------------- MFMA flash attention: K/V dbuf, XCD swizzle, stride-72 LDS -------------
// Round-13 measured-best body (stride 72 = 16B-aligned rows; the 5.77M conflict counter is
// benign floor-aliasing -- stride-68 "fix" removed it but broke b128 alignment, -7%).
// Staging HOISTED to the top of each iteration (write tile kt+1 regs -> buf c^1 + issue
// tile kt+2 loads right after the barrier) so the ds_writes retire under the
// QK^T/softmax/PV stream instead of just before the barrier's lgkm drain. Buffer safety:
// buf c^1's readers completed before the barrier we just passed.
__global__ __launch_bounds__(256) void k_attn_mfma(const unsigned short* __restrict__ qkv,
                                                   unsigned short* __restrict__ xatt) {
    __shared__ unsigned short Ks[2][64 * 72];    // K tile [key][d], double-buffered
    __shared__ unsigned short Vt[2][64 * 72];    // V^T tile [d][key], double-buffered
    __shared__ unsigned short Pls[64 * 72];      // P tile [m][key] (wave-private rows)

    // grid (32, 8, 2), nwg=512, cpx=64 -- bijective XCD swizzle
    int flat = (blockIdx.z * HH + blockIdx.y) * (NN / 64) + blockIdx.x;
    int swz = (flat & 7) * 64 + (flat >> 3);
    int qt = swz & 31;
    int hb = swz >> 5;
    int hd = hb & 7, b = hb >> 3;

    int tid = threadIdx.x;
    int l = tid & 63, w = tid >> 6;
    int lr = l & 15, quad = l >> 4;

    const size_t base = (size_t)b * NN * 1536;

    // Q frags (B-operand): lane col m=lr, k=d=quad*8+j (+32*ss)
    short8 qf[2];
    {
        const unsigned short* qrow = qkv + base + (size_t)(qt * 64 + w * 16 + lr) * 1536 + hd * 64;
        qf[0] = *(const short8*)&qrow[quad * 8];
        qf[1] = *(const short8*)&qrow[quad * 8 + 32];
    }

    floatx4 O[4];   // O[m=quad*4+reg][d=jd*16+lr]
#pragma unroll
    for (int jd = 0; jd < 4; jd++) O[jd] = (floatx4){0.f, 0.f, 0.f, 0.f};
    float lsum = 0.0f;   // per-lane partial row-sum for query m = w*16+lr

    // staging maps; running pointers bumped by constant stride (cheap VALU)
    int sr = tid >> 2, sc = (tid & 3) * 16;          // K: row sr (key), 16-d chunk sc
    int vk = (tid & 15) * 4, vd = (tid >> 4) * 4;    // V: 4 keys x 4 d per thread
    const int STEP = 64 * 1536;                      // one 64-key tile
    const unsigned short* Kp = qkv + base + 512 + hd * 64 + (size_t)sr * 1536 + sc;
    const unsigned short* Vp = qkv + base + 1024 + hd * 64 + (size_t)vk * 1536 + vd;

    uint4 rk0, rk1;
    union { uint2 u; unsigned short s[4]; } rv[4];

    // prologue: load tile 0, write to buf 0, load tile 1, barrier
    rk0 = *(const uint4*)Kp;
    rk1 = *(const uint4*)(Kp + 8);
#pragma unroll
    for (int i = 0; i < 4; i++)
        rv[i].u = *(const uint2*)(Vp + (size_t)i * 1536);
    *(uint4*)&Ks[0][sr * 72 + sc]     = rk0;
    *(uint4*)&Ks[0][sr * 72 + sc + 8] = rk1;
#pragma unroll
    for (int j = 0; j < 4; j++) {
        union { uint2 u; unsigned short s[4]; } pk;
        pk.s[0] = rv[0].s[j]; pk.s[1] = rv[1].s[j];
        pk.s[2] = rv[2].s[j]; pk.s[3] = rv[3].s[j];
        *(uint2*)&Vt[0][(vd + j) * 72 + vk] = pk.u;
    }
    Kp += STEP; Vp += STEP;
    rk0 = *(const uint4*)Kp;
    rk1 = *(const uint4*)(Kp + 8);
#pragma unroll
    for (int i = 0; i < 4; i++)
        rv[i].u = *(const uint2*)(Vp + (size_t)i * 1536);
    __syncthreads();

    // exp(s/8 - 8) = exp2(s * (0.125*log2e) - 8*log2e)
    const float EC1 = 0.18033688011112042f;
    const float EC0 = -11.541560327111707f;

    for (int kt = 0; kt < 32; kt++) {
        int c = kt & 1;

        // HOISTED staging: write tile kt+1 (in regs) -> buf c^1 NOW (readers of c^1 passed
        // the previous barrier); then issue tile kt+2 loads -- all retire under the MFMA
        // and softmax stream below.
        if (kt < 31) {
            *(uint4*)&Ks[c ^ 1][sr * 72 + sc]     = rk0;
            *(uint4*)&Ks[c ^ 1][sr * 72 + sc + 8] = rk1;
#pragma unroll
            for (int j = 0; j < 4; j++) {
                union { uint2 u; unsigned short s[4]; } pk;
                pk.s[0] = rv[0].s[j]; pk.s[1] = rv[1].s[j];
                pk.s[2] = rv[2].s[j]; pk.s[3] = rv[3].s[j];
                *(uint2*)&Vt[c ^ 1][(vd + j) * 72 + vk] = pk.u;
            }
            if (kt < 30) {
                Kp += STEP; Vp += STEP;
                rk0 = *(const uint4*)Kp;
                rk1 = *(const uint4*)(Kp + 8);
#pragma unroll
                for (int i = 0; i < 4; i++)
                    rv[i].u = *(const uint2*)(Vp + (size_t)i * 1536);
            }
        }

        // S^T = K Q^T: s[jn] rows key=jn*16+quad*4+reg, col m=lr
        floatx4 s[4];
#pragma unroll
        for (int jn = 0; jn < 4; jn++) s[jn] = (floatx4){0.f, 0.f, 0.f, 0.f};
#pragma unroll
        for (int ss = 0; ss < 2; ss++)
#pragma unroll
            for (int jn = 0; jn < 4; jn++) {
                short8 ak = *(const short8*)&Ks[c][(jn * 16 + lr) * 72 + ss * 32 + quad * 8];
                s[jn] = __builtin_amdgcn_mfma_f32_16x16x32_bf16(ak, qf[ss], s[jn], 0, 0, 0);
            }

        // p = exp2(s*EC1 + EC0); diag mask (uniform branch, 1/32 iters); lsum; pk pack
        int mq = w * 16 + lr;   // query index within 64-row q tile
        bool diag = (kt == qt);
#pragma unroll
        for (int jn = 0; jn < 4; jn++) {
            float p0 = __builtin_amdgcn_exp2f(fmaf(s[jn][0], EC1, EC0));
            float p1 = __builtin_amdgcn_exp2f(fmaf(s[jn][1], EC1, EC0));
            float p2 = __builtin_amdgcn_exp2f(fmaf(s[jn][2], EC1, EC0));
            float p3 = __builtin_amdgcn_exp2f(fmaf(s[jn][3], EC1, EC0));
            if (diag) {   // wave-uniform: taken in exactly one kt iteration
                int kbase = jn * 16 + quad * 4;
                if (mq == kbase + 0) p0 = 0.0f;
                if (mq == kbase + 1) p1 = 0.0f;
                if (mq == kbase + 2) p2 = 0.0f;
                if (mq == kbase + 3) p3 = 0.0f;
            }
            lsum += (p0 + p1) + (p2 + p3);
            unsigned w01, w23;
            asm("v_cvt_pk_bf16_f32 %0, %1, %2" : "=v"(w01) : "v"(p0), "v"(p1));
            asm("v_cvt_pk_bf16_f32 %0, %1, %2" : "=v"(w23) : "v"(p2), "v"(p3));
            uint2 pku; pku.x = w01; pku.y = w23;
            *(uint2*)&Pls[mq * 72 + jn * 16 + quad * 4] = pku;
        }

        // O += P V   (P rows written/read by the same wave; no barrier needed)
#pragma unroll
        for (int ss = 0; ss < 2; ss++) {
            short8 ap = *(const short8*)&Pls[(w * 16 + lr) * 72 + ss * 32 + quad * 8];
#pragma unroll
            for (int jd = 0; jd < 4; jd++) {
                short8 bv = *(const short8*)&Vt[c][(jd * 16 + lr) * 72 + ss * 32 + quad * 8];
                O[jd] = __builtin_amdgcn_mfma_f32_16x16x32_bf16(ap, bv, O[jd], 0, 0, 0);
            }
        }

        __syncthreads();   // buf c readers done + buf c^1 fully written
    }

    // reduce lsum across quads (lanes lr, lr+16, lr+32, lr+48 hold same query)
    lsum += __shfl_xor(lsum, 16);
    lsum += __shfl_xor(lsum, 32);
#pragma unroll
    for (int r = 0; r < 4; r++) {
        float inv = 1.0f / __shfl(lsum, quad * 4 + r, 16);
        size_t tok = (size_t)b * NN + qt * 64 + w * 16 + quad * 4 + r;
#pragma unroll
        for (int jd = 0; jd < 4; jd++)
            xatt[tok * DD + hd * 64 + jd * 16 + lr] = f2b(O[jd][r] * inv);
    }
}

extern "C" void kernel_launch(void* const* d_in, const int* in_sizes, int n_in,
                              void* d_out, int out_size, void* d_ws, size_t ws_size,
                              hipStream_t stream) {
    const float* emb      = (const float*)d_in[0];
    const float* pos      = (const float*)d_in[1];
    const float* c_attn_w = (const float*)d_in[2];
    const float* c_attn_b = (const float*)d_in[3];
    const float* out_w    = (const float*)d_in[4];
    const float* out_b    = (const float*)d_in[5];
    const float* ln1_g    = (const float*)d_in[6];
    const float* ln1_b    = (const float*)d_in[7];
    const float* c_fc_w   = (const float*)d_in[8];
    const float* c_fc_b   = (const float*)d_in[9];
    const float* c_proj_w = (const float*)d_in[10];
    const float* c_proj_b = (const float*)d_in[11];
    const float* ln2_g    = (const float*)d_in[12];
    const float* ln2_b    = (const float*)d_in[13];

    // workspace: 8 + 16.8 + 4 + 4 + 12.6 = ~45.4 MB
    char* p = (char*)d_ws;
    float* h = (float*)p;                       p += (size_t)TT * DD * 4;      // fp32 residual
    unsigned short* act = (unsigned short*)p;   p += (size_t)TT * 2048 * 2;    // qkvb/ffa union
    unsigned short* x = (unsigned short*)p;     p += (size_t)TT * DD * 2;      // LN out
    unsigned short* xatt = (unsigned short*)p;  p += (size_t)TT * DD * 2;      // attn out
    unsigned short* wbuf = (unsigned short*)p;                                 // bf16 W^T (both layers)

    unsigned short* qkvb = act;
    unsigned short* ffa  = act;
    float* out = (float*)d_out;

    k_wt_all<<<1536, 256, 0, stream>>>(c_attn_w, out_w, c_fc_w, c_proj_w, wbuf);

    for (int l = 0; l < LL; l++) {
        unsigned short* wqkv_t  = wbuf + (size_t)l * PL;
        unsigned short* wout_t  = wqkv_t + 786432;
        unsigned short* wfc_t   = wqkv_t + 1048576;
        unsigned short* wproj_t = wqkv_t + 2097152;

        // x = LN1(h)  (layer 0: fused embed, also writes h)
        if (l == 0)
            k_ln<1><<<TT, 256, 0, stream>>>(nullptr, x, ln1_g, ln1_b, emb, pos, h);
        else
            k_ln<0><<<TT, 256, 0, stream>>>(h, x, ln1_g + l * DD, ln1_b + l * DD,
                                            nullptr, nullptr, nullptr);
        // qkvb = x @ Wqkv + b  (bf16)
        k_mgemm<0, 1, 0><<<dim3(1536 / 128, TT / 128), 512, 0, stream>>>(
            x, wqkv_t, c_attn_b + l * 1536, nullptr, qkvb, 512, 512, 1536);
        // xatt = attention(qkvb)  (bf16)
        k_attn_mfma<<<dim3(NN / 64, HH, BB), 256, 0, stream>>>(qkvb, xatt);
        // h += xatt @ Wout + out_b  (split-K=2 fp32 atomics; bias folded into z==0)
        k_mgemm<0, 0, 1><<<dim3(512 / 128, TT / 128, 2), 512, 0, stream>>>(
            xatt, wout_t, out_b + l * DD, h, nullptr, 512, 256, 512);
        // x = LN2(h)
        k_ln<0><<<TT, 256, 0, stream>>>(h, x, ln2_g + l * DD, ln2_b + l * DD,
                                        nullptr, nullptr, nullptr);
        // ffa = gelu(x @ Wfc + b)  (bf16; qkvb dead)
        k_mgemm<1, 1, 0><<<dim3(2048 / 128, TT / 128), 512, 0, stream>>>(
            x, wfc_t, c_fc_b + l * 2048, nullptr, ffa, 512, 512, 2048);
        // h/out += ffa @ Wproj + proj_b  (split-K=4 fp32 atomics)
        if (l == LL - 1) {
            k_bias_add<<<TT * DD / 256, 256, 0, stream>>>(h, c_proj_b + l * DD, out);
            k_mgemm<0, 0, 1><<<dim3(512 / 128, TT / 128, 4), 512, 0, stream>>>(
                ffa, wproj_t, nullptr, out, nullptr, 2048, 512, 512);
        } else {
            k_mgemm<0, 0, 1><<<dim3(512 / 128, TT / 128, 4), 512, 0, stream>>>(
                ffa, wproj_t, c_proj_b + l * DD, h, nullptr, 2048, 512, 512);
        }
    }
}